// Round 16
// baseline (76.211 us; speedup 1.0000x reference)
//
#include <hip/hip_runtime.h>

#define IN_DIM 256
#define OUT_DIM 128
#define SLOPE 0.1f
#define CAP 128   // per-dst bucket capacity; filtered degree ~ Poisson(33), max ~70

typedef short bf16x8 __attribute__((ext_vector_type(8)));
typedef float f32x4  __attribute__((ext_vector_type(4)));

__device__ __forceinline__ unsigned short f2bf(float f) {
    unsigned u = __builtin_bit_cast(unsigned, f);
    return (unsigned short)((u + 0x7FFFu + ((u >> 16) & 1u)) >> 16);   // RNE
}

__device__ __forceinline__ void pack8(const float4& v0, const float4& v1, bf16x8& pk) {
    pk[0]=(short)f2bf(v0.x); pk[1]=(short)f2bf(v0.y);
    pk[2]=(short)f2bf(v0.z); pk[3]=(short)f2bf(v0.w);
    pk[4]=(short)f2bf(v1.x); pk[5]=(short)f2bf(v1.y);
    pk[6]=(short)f2bf(v1.z); pk[7]=(short)f2bf(v1.w);
}

// ---------------------------------------------------------------------------
// Kernel 1 (R16 restructure): emb = feats @ W^T + b.
// W (128x256 = 64KB bf16) staged to LDS ONCE; then a BARRIER-FREE grid-stride
// stream: each wave owns 16-row chunks, loads A-fragments directly from
// global (fragment layout == row-major global layout, no LDS round trip),
// 64 MFMA vs LDS-resident W, fused bias+scores+bf16-emb epilogue.
// Rationale: K=256 gave only 2 barrier phases (two exposed latency round
// trips, nothing to pipeline). R13/14/15 staging rewrites all null.
// ---------------------------------------------------------------------------
__global__ __launch_bounds__(256) void gemm_mfma_kernel(
    const float* __restrict__ feats, const float* __restrict__ W,
    const float* __restrict__ bias, const float* __restrict__ a,
    unsigned short* __restrict__ emb_bf, float* __restrict__ s_dst,
    float* __restrict__ s_src, int* __restrict__ needed,
    int* __restrict__ cur, int n, int nchunks)
{
    __shared__ __align__(16) unsigned short W_s[128 * 256];   // 64KB

    const int t    = threadIdx.x;
    const int lane = t & 63;
    const int wid  = t >> 6;

    // fused scratch init (grid covers n: 512 blocks x 256 = 131072 >= n)
    const int gi = blockIdx.x * 256 + t;
    if (gi < n) { needed[gi] = 0; cur[gi] = 0; }

    // ---- stage ALL of W once (bf16, XOR-swizzled rows of 256) ----
    #pragma unroll
    for (int i = 0; i < 16; ++i) {
        const int g = i * 256 + t;      // 0..4095 chunks of 8 elems
        const int r = g >> 5;           // W row (output col) 0..127
        const int c = g & 31;           // 8-elem chunk within row
        const float* p = &W[(size_t)r * IN_DIM + c * 8];
        const float4 v0 = *(const float4*)p;
        const float4 v1 = *(const float4*)(p + 4);
        bf16x8 pk; pack8(v0, v1, pk);
        *(bf16x8*)&W_s[r * 256 + ((c ^ (r & 7)) << 3)] = pk;
    }
    __syncthreads();   // the ONLY barrier

    // per-lane constants
    const int rl = lane & 15;      // row-in-chunk == col-in-tile selector
    const int kq = lane >> 4;      // k-quarter selector
    float bcol[8], avd[8], avs[8];
    #pragma unroll
    for (int ni = 0; ni < 8; ++ni) {
        const int col = ni * 16 + rl;
        bcol[ni] = bias[col];
        avd[ni]  = a[col];
        avs[ni]  = a[OUT_DIM + col];
    }

    const int wstart  = blockIdx.x * 4 + wid;
    const int wstride = gridDim.x * 4;

    for (int chunk = wstart; chunk < nchunks; chunk += wstride) {
        const int row0 = chunk * 16;
        const int arow = row0 + rl;
        const int lrow = arow < n ? arow : n - 1;   // clamp (tail safety)
        const float* prow = &feats[(size_t)lrow * IN_DIM + kq * 8];

        // ---- A fragments straight from global: 16 independent float4 loads ----
        bf16x8 af[8];
        #pragma unroll
        for (int ks = 0; ks < 8; ++ks) {
            const float4 v0 = *(const float4*)(prow + ks * 32);
            const float4 v1 = *(const float4*)(prow + ks * 32 + 4);
            pack8(v0, v1, af[ks]);
        }

        f32x4 acc[8];
        #pragma unroll
        for (int ni = 0; ni < 8; ++ni) acc[ni] = {0.f, 0.f, 0.f, 0.f};

        // ---- 8 K-steps x 8 N-tiles of MFMA vs LDS-resident W ----
        #pragma unroll
        for (int ks = 0; ks < 8; ++ks) {
            const int kf = ks * 32 + kq * 8;
            #pragma unroll
            for (int ni = 0; ni < 8; ++ni) {
                const int col = ni * 16 + rl;
                const int off = (col * 256 + kf) ^ ((col & 7) << 3);
                const bf16x8 wf = *(const bf16x8*)&W_s[off];
                acc[ni] = __builtin_amdgcn_mfma_f32_16x16x32_bf16(
                    af[ks], wf, acc[ni], 0, 0, 0);
            }
        }

        // ---- epilogue: bias, bf16 emb store, fused score partials ----
        float pd[4] = {0.f,0.f,0.f,0.f}, ps[4] = {0.f,0.f,0.f,0.f};
        #pragma unroll
        for (int ni = 0; ni < 8; ++ni) {
            #pragma unroll
            for (int j = 0; j < 4; ++j) {
                const float v = acc[ni][j] + bcol[ni];
                const int row = row0 + kq * 4 + j;
                if (row < n)
                    emb_bf[(size_t)row * OUT_DIM + ni * 16 + rl] = f2bf(v);
                pd[j] = fmaf(v, avd[ni], pd[j]);
                ps[j] = fmaf(v, avs[ni], ps[j]);
            }
        }
        #pragma unroll
        for (int j = 0; j < 4; ++j) {
            pd[j] += __shfl_xor(pd[j], 1); ps[j] += __shfl_xor(ps[j], 1);
            pd[j] += __shfl_xor(pd[j], 2); ps[j] += __shfl_xor(ps[j], 2);
            pd[j] += __shfl_xor(pd[j], 4); ps[j] += __shfl_xor(ps[j], 4);
            pd[j] += __shfl_xor(pd[j], 8); ps[j] += __shfl_xor(ps[j], 8);
            const int row = row0 + kq * 4 + j;
            if (rl == 0 && row < n) {
                s_dst[row] = pd[j];
                s_src[row] = ps[j];
            }
        }
    }
}

// ---------------------------------------------------------------------------
// Kernel 2: mark needed destinations (plain store; idempotent)
// ---------------------------------------------------------------------------
__global__ void flag_kernel(const int* __restrict__ node_idx,
                            int* __restrict__ needed, int nb)
{
    const int i = blockIdx.x * blockDim.x + threadIdx.x;
    if (i < nb) needed[node_idx[i]] = 1;
}

// ---------------------------------------------------------------------------
// Kernel 3: needed-filtered scatter into per-dst buckets (R7-proven form).
// ---------------------------------------------------------------------------
__global__ __launch_bounds__(256) void scatter_kernel(
    const int* __restrict__ edges, const int* __restrict__ needed,
    int* __restrict__ cur, const float* __restrict__ s_dst,
    const float* __restrict__ s_src, int2* __restrict__ ew, int E)
{
    const int e = blockIdx.x * blockDim.x + threadIdx.x;
    if (e >= E) return;
    const int2 ed = reinterpret_cast<const int2*>(edges)[e];
    if (needed[ed.x]) {
        const float x = s_dst[ed.x] + s_src[ed.y];
        const float w = __expf(x >= 0.f ? x : SLOPE * x);
        const int p = atomicAdd(&cur[ed.x], 1);
        if (p < CAP)
            ew[(size_t)ed.x * CAP + p] = make_int2(ed.y, __float_as_int(w));
    }
}

// ---------------------------------------------------------------------------
// Kernel 4: fused aggregate + output (R7-proven form).
// ---------------------------------------------------------------------------
__global__ __launch_bounds__(256) void agg_out_kernel(
    const int* __restrict__ node_idx, const int* __restrict__ cur,
    const int2* __restrict__ ew, const unsigned short* __restrict__ emb_bf,
    float* __restrict__ out, int nb)
{
    const int w    = (int)((blockIdx.x * blockDim.x + threadIdx.x) >> 6);
    const int lane = threadIdx.x & 63;
    if (w >= nb) return;

    const int dst = node_idx[w];
    int m = cur[dst];
    if (m > CAP) m = CAP;
    const int2* __restrict__ bucket = ew + (size_t)dst * CAP;

    float accx = 0.f, accy = 0.f, den = 0.f;

    for (int base = 0; base < m; base += 64) {
        const int rem = min(64, m - base);
        int   src = 0;
        float wt  = 0.f;
        if (lane < rem) {
            const int2 q = bucket[base + lane];
            src = q.x;
            wt  = __int_as_float(q.y);
        }
        int i = 0;
        for (; i + 4 <= rem; i += 4) {
            const int   s0 = __shfl(src, i),     s1 = __shfl(src, i + 1);
            const int   s2 = __shfl(src, i + 2), s3 = __shfl(src, i + 3);
            const float w0 = __shfl(wt, i),      w1 = __shfl(wt, i + 1);
            const float w2 = __shfl(wt, i + 2),  w3 = __shfl(wt, i + 3);
            const unsigned b0 = *(const unsigned*)&emb_bf[(size_t)s0 * OUT_DIM + 2 * lane];
            const unsigned b1 = *(const unsigned*)&emb_bf[(size_t)s1 * OUT_DIM + 2 * lane];
            const unsigned b2 = *(const unsigned*)&emb_bf[(size_t)s2 * OUT_DIM + 2 * lane];
            const unsigned b3 = *(const unsigned*)&emb_bf[(size_t)s3 * OUT_DIM + 2 * lane];
            den += (w0 + w1) + (w2 + w3);
            accx = fmaf(w0, __int_as_float((int)(b0 << 16)), accx);
            accy = fmaf(w0, __int_as_float((int)(b0 & 0xFFFF0000u)), accy);
            accx = fmaf(w1, __int_as_float((int)(b1 << 16)), accx);
            accy = fmaf(w1, __int_as_float((int)(b1 & 0xFFFF0000u)), accy);
            accx = fmaf(w2, __int_as_float((int)(b2 << 16)), accx);
            accy = fmaf(w2, __int_as_float((int)(b2 & 0xFFFF0000u)), accy);
            accx = fmaf(w3, __int_as_float((int)(b3 << 16)), accx);
            accy = fmaf(w3, __int_as_float((int)(b3 & 0xFFFF0000u)), accy);
        }
        for (; i < rem; ++i) {
            const int   s0 = __shfl(src, i);
            const float w0 = __shfl(wt, i);
            const unsigned b0 = *(const unsigned*)&emb_bf[(size_t)s0 * OUT_DIM + 2 * lane];
            den += w0;
            accx = fmaf(w0, __int_as_float((int)(b0 << 16)), accx);
            accy = fmaf(w0, __int_as_float((int)(b0 & 0xFFFF0000u)), accy);
        }
    }

    const float inv = 1.0f / den;
    float2 o; o.x = accx * inv; o.y = accy * inv;
    *reinterpret_cast<float2*>(&out[(size_t)w * OUT_DIM + 2 * lane]) = o;
}

// ---------------------------------------------------------------------------
extern "C" void kernel_launch(void* const* d_in, const int* in_sizes, int n_in,
                              void* d_out, int out_size, void* d_ws, size_t ws_size,
                              hipStream_t stream)
{
    const float* feats    = (const float*)d_in[0];
    const float* W        = (const float*)d_in[1];
    const float* bias     = (const float*)d_in[2];
    const float* a        = (const float*)d_in[3];
    const int*   edges    = (const int*)d_in[4];
    const int*   node_idx = (const int*)d_in[5];
    float*       out      = (float*)d_out;

    const int n  = in_sizes[0] / IN_DIM;   // 50000
    const int E  = in_sizes[4] / 2;        // 1650000
    const int nb = in_sizes[5];            // 10000
    const int nchunks = (n + 15) / 16;     // 3125 (exact: 50000 = 16*3125)

    // Workspace layout (16B-aligned segments):
    char* ws = (char*)d_ws;
    unsigned short* emb_bf = (unsigned short*)ws;
    ws += (size_t)n * OUT_DIM * sizeof(unsigned short);                 // 12.8 MB
    float* s_dst = (float*)ws;  ws += (size_t)(n + 4) * sizeof(float);
    float* s_src = (float*)ws;  ws += (size_t)(n + 4) * sizeof(float);
    int*   needed= (int*)ws;    ws += (size_t)(n + 4) * sizeof(int);
    int*   cur   = (int*)ws;    ws += (size_t)(n + 4) * sizeof(int);
    int2*  ew    = (int2*)ws;   ws += (size_t)n * CAP * sizeof(int2);   // 51.2 MB

    gemm_mfma_kernel<<<512, 256, 0, stream>>>(
        feats, W, bias, a, emb_bf, s_dst, s_src, needed, cur, n, nchunks);
    flag_kernel     <<<(nb + 255) / 256, 256, 0, stream>>>(node_idx, needed, nb);
    scatter_kernel  <<<(E + 255) / 256, 256, 0, stream>>>(edges, needed, cur, s_dst, s_src, ew, E);
    agg_out_kernel  <<<(nb + 3) / 4, 256, 0, stream>>>(node_idx, cur, ew, emb_bf, out, nb);
}

// Round 17
// 66.897 us; speedup vs baseline: 1.1392x; 1.1392x over previous
//
#include <hip/hip_runtime.h>

#define IN_DIM 256
#define OUT_DIM 128
#define SLOPE 0.1f
#define CAP 128   // per-dst bucket capacity; filtered degree ~ Poisson(33), max ~70

typedef short bf16x8 __attribute__((ext_vector_type(8)));
typedef float f32x4  __attribute__((ext_vector_type(4)));

__device__ __forceinline__ unsigned short f2bf(float f) {
    unsigned u = __builtin_bit_cast(unsigned, f);
    return (unsigned short)((u + 0x7FFFu + ((u >> 16) & 1u)) >> 16);   // RNE
}

__device__ __forceinline__ void pack8(const float4& v0, const float4& v1, bf16x8& pk) {
    pk[0]=(short)f2bf(v0.x); pk[1]=(short)f2bf(v0.y);
    pk[2]=(short)f2bf(v0.z); pk[3]=(short)f2bf(v0.w);
    pk[4]=(short)f2bf(v1.x); pk[5]=(short)f2bf(v1.y);
    pk[6]=(short)f2bf(v1.z); pk[7]=(short)f2bf(v1.w);
}

// async 16B global->LDS DMA; LDS dest is wave-uniform base + lane*16
__device__ __forceinline__ void gld_lds16(const void* g, void* l) {
    __builtin_amdgcn_global_load_lds(
        (const __attribute__((address_space(1))) void*)g,
        (__attribute__((address_space(3))) void*)l, 16, 0, 0);
}

// ---------------------------------------------------------------------------
// Kernel 1 (R17): emb = feats @ W^T + b via bf16 MFMA.
// Combines the two measured levers: async global_load_lds staging (R13: the
// only gemm improvement measured, no VGPR round-trip) + high occupancy
// (R16 showed 2 waves/SIMD from VGPR/LDS pressure is the latency killer).
// BM=64, K-phase=64, fp32 DMA'd raw (convert at LDS-read), LDS 49.5KB ->
// 3 blocks/CU, 782 blocks = 3.05/CU, one resident round, ~12 waves/CU.
// Swizzle on DMA SOURCE addr (linear LDS dest), same XOR on read (rule 21).
// Fused: s_dst/s_src scores; needed[]/cur[] init; emb stored bf16.
// ---------------------------------------------------------------------------
__global__ __launch_bounds__(256) void gemm_mfma_kernel(
    const float* __restrict__ feats, const float* __restrict__ W,
    const float* __restrict__ bias, const float* __restrict__ a,
    unsigned short* __restrict__ emb_bf, float* __restrict__ s_dst,
    float* __restrict__ s_src, int* __restrict__ needed,
    int* __restrict__ cur, int n)
{
    __shared__ __align__(16) float A_s[64 * 64];     // 16KB: 64 rows x 64k fp32
    __shared__ __align__(16) float W_s[128 * 64];    // 32KB: 128 cols x 64k fp32
    __shared__ float sd_l[2][64];
    __shared__ float ss_l[2][64];

    const int t    = threadIdx.x;
    const int lane = t & 63;
    const int wid  = t >> 6;
    const int wr   = wid >> 1;          // 0..1 : 32-row half
    const int wc   = wid & 1;           // 0..1 : 64-col half
    const int row0 = blockIdx.x * 64;

    // fused scratch init
    if (t < 64) {
        const int ci = row0 + t;
        if (ci < n) { needed[ci] = 0; cur[ci] = 0; }
    }

    const int rlo4 = lane >> 4;   // 0..3 : row within a 4-row DMA issue
    const int b16  = lane & 15;   // 16B chunk within a 256B row-slice

    const f32x4 z4 = {0.f, 0.f, 0.f, 0.f};
    f32x4 acc[2][4];
    #pragma unroll
    for (int mi = 0; mi < 2; ++mi)
        #pragma unroll
        for (int ni = 0; ni < 4; ++ni) acc[mi][ni] = z4;

    for (int ph = 0; ph < 4; ++ph) {
        const int k0 = ph * 64;
        if (ph) __syncthreads();

        // ---- A: 4 DMA issues/wave (64 rows x 256B) ----
        #pragma unroll
        for (int j = 0; j < 4; ++j) {
            const int r  = wid * 16 + j * 4 + rlo4;          // 0..63
            const int gr = min(row0 + r, n - 1);             // clamp: tail-safe
            const int ch = b16 ^ ((r & 7) << 1);             // pre-swizzled source
            gld_lds16(feats + (size_t)gr * IN_DIM + k0 + (ch << 2),
                      &A_s[(wid * 16 + j * 4) * 64]);
        }
        // ---- W: 8 DMA issues/wave (128 cols x 256B) ----
        #pragma unroll
        for (int j = 0; j < 8; ++j) {
            const int c  = wid * 32 + j * 4 + rlo4;          // 0..127
            const int ch = b16 ^ ((c & 7) << 1);
            gld_lds16(W + (size_t)c * IN_DIM + k0 + (ch << 2),
                      &W_s[(wid * 32 + j * 4) * 64]);
        }
        __syncthreads();   // compiler drains vmcnt here -> tiles complete

        // ---- compute: 2 K-steps of 32, convert fp32->bf16 at read ----
        #pragma unroll
        for (int ks = 0; ks < 2; ++ks) {
            const int c0 = ks * 8 + (lane >> 4) * 2;   // even 16B-chunk index
            bf16x8 af[2], wf[4];
            #pragma unroll
            for (int mi = 0; mi < 2; ++mi) {
                const int row = wr * 32 + mi * 16 + (lane & 15);
                const int cc  = c0 ^ ((row & 7) << 1);
                const float4 f0 = *(const float4*)&A_s[row * 64 + cc * 4];
                const float4 f1 = *(const float4*)&A_s[row * 64 + cc * 4 + 4];
                pack8(f0, f1, af[mi]);
            }
            #pragma unroll
            for (int ni = 0; ni < 4; ++ni) {
                const int col = wc * 64 + ni * 16 + (lane & 15);
                const int cc  = c0 ^ ((col & 7) << 1);
                const float4 f0 = *(const float4*)&W_s[col * 64 + cc * 4];
                const float4 f1 = *(const float4*)&W_s[col * 64 + cc * 4 + 4];
                pack8(f0, f1, wf[ni]);
            }
            #pragma unroll
            for (int mi = 0; mi < 2; ++mi)
                #pragma unroll
                for (int ni = 0; ni < 4; ++ni)
                    acc[mi][ni] = __builtin_amdgcn_mfma_f32_16x16x32_bf16(
                        af[mi], wf[ni], acc[mi][ni], 0, 0, 0);
        }
    }

    // ---- epilogue: bias, bf16 emb store, fused score partials ----
    float bcol[4], avd[4], avs[4];
    #pragma unroll
    for (int ni = 0; ni < 4; ++ni) {
        const int col = wc * 64 + ni * 16 + (lane & 15);
        bcol[ni] = bias[col];
        avd[ni]  = a[col];
        avs[ni]  = a[OUT_DIM + col];
    }

    #pragma unroll
    for (int mi = 0; mi < 2; ++mi) {
        #pragma unroll
        for (int j = 0; j < 4; ++j) {
            const int rib = wr * 32 + mi * 16 + (lane >> 4) * 4 + j;
            const int row = row0 + rib;
            float pd = 0.f, ps = 0.f;
            if (row < n) {
                #pragma unroll
                for (int ni = 0; ni < 4; ++ni) {
                    const float v = acc[mi][ni][j] + bcol[ni];
                    emb_bf[(size_t)row * OUT_DIM + wc * 64 + ni * 16 + (lane & 15)] = f2bf(v);
                    pd = fmaf(v, avd[ni], pd);
                    ps = fmaf(v, avs[ni], ps);
                }
            }
            pd += __shfl_xor(pd, 1); ps += __shfl_xor(ps, 1);
            pd += __shfl_xor(pd, 2); ps += __shfl_xor(ps, 2);
            pd += __shfl_xor(pd, 4); ps += __shfl_xor(ps, 4);
            pd += __shfl_xor(pd, 8); ps += __shfl_xor(ps, 8);
            if ((lane & 15) == 0) { sd_l[wc][rib] = pd; ss_l[wc][rib] = ps; }
        }
    }
    __syncthreads();
    if (t < 64) {
        const int row = row0 + t;
        if (row < n) {
            s_dst[row] = sd_l[0][t] + sd_l[1][t];
            s_src[row] = ss_l[0][t] + ss_l[1][t];
        }
    }
}

// ---------------------------------------------------------------------------
// Kernel 2: mark needed destinations (plain store; idempotent)
// ---------------------------------------------------------------------------
__global__ void flag_kernel(const int* __restrict__ node_idx,
                            int* __restrict__ needed, int nb)
{
    const int i = blockIdx.x * blockDim.x + threadIdx.x;
    if (i < nb) needed[node_idx[i]] = 1;
}

// ---------------------------------------------------------------------------
// Kernel 3: needed-filtered scatter into per-dst buckets (R7-proven form).
// ---------------------------------------------------------------------------
__global__ __launch_bounds__(256) void scatter_kernel(
    const int* __restrict__ edges, const int* __restrict__ needed,
    int* __restrict__ cur, const float* __restrict__ s_dst,
    const float* __restrict__ s_src, int2* __restrict__ ew, int E)
{
    const int e = blockIdx.x * blockDim.x + threadIdx.x;
    if (e >= E) return;
    const int2 ed = reinterpret_cast<const int2*>(edges)[e];
    if (needed[ed.x]) {
        const float x = s_dst[ed.x] + s_src[ed.y];
        const float w = __expf(x >= 0.f ? x : SLOPE * x);
        const int p = atomicAdd(&cur[ed.x], 1);
        if (p < CAP)
            ew[(size_t)ed.x * CAP + p] = make_int2(ed.y, __float_as_int(w));
    }
}

// ---------------------------------------------------------------------------
// Kernel 4: fused aggregate + output (R7-proven form).
// ---------------------------------------------------------------------------
__global__ __launch_bounds__(256) void agg_out_kernel(
    const int* __restrict__ node_idx, const int* __restrict__ cur,
    const int2* __restrict__ ew, const unsigned short* __restrict__ emb_bf,
    float* __restrict__ out, int nb)
{
    const int w    = (int)((blockIdx.x * blockDim.x + threadIdx.x) >> 6);
    const int lane = threadIdx.x & 63;
    if (w >= nb) return;

    const int dst = node_idx[w];
    int m = cur[dst];
    if (m > CAP) m = CAP;
    const int2* __restrict__ bucket = ew + (size_t)dst * CAP;

    float accx = 0.f, accy = 0.f, den = 0.f;

    for (int base = 0; base < m; base += 64) {
        const int rem = min(64, m - base);
        int   src = 0;
        float wt  = 0.f;
        if (lane < rem) {
            const int2 q = bucket[base + lane];
            src = q.x;
            wt  = __int_as_float(q.y);
        }
        int i = 0;
        for (; i + 4 <= rem; i += 4) {
            const int   s0 = __shfl(src, i),     s1 = __shfl(src, i + 1);
            const int   s2 = __shfl(src, i + 2), s3 = __shfl(src, i + 3);
            const float w0 = __shfl(wt, i),      w1 = __shfl(wt, i + 1);
            const float w2 = __shfl(wt, i + 2),  w3 = __shfl(wt, i + 3);
            const unsigned b0 = *(const unsigned*)&emb_bf[(size_t)s0 * OUT_DIM + 2 * lane];
            const unsigned b1 = *(const unsigned*)&emb_bf[(size_t)s1 * OUT_DIM + 2 * lane];
            const unsigned b2 = *(const unsigned*)&emb_bf[(size_t)s2 * OUT_DIM + 2 * lane];
            const unsigned b3 = *(const unsigned*)&emb_bf[(size_t)s3 * OUT_DIM + 2 * lane];
            den += (w0 + w1) + (w2 + w3);
            accx = fmaf(w0, __int_as_float((int)(b0 << 16)), accx);
            accy = fmaf(w0, __int_as_float((int)(b0 & 0xFFFF0000u)), accy);
            accx = fmaf(w1, __int_as_float((int)(b1 << 16)), accx);
            accy = fmaf(w1, __int_as_float((int)(b1 & 0xFFFF0000u)), accy);
            accx = fmaf(w2, __int_as_float((int)(b2 << 16)), accx);
            accy = fmaf(w2, __int_as_float((int)(b2 & 0xFFFF0000u)), accy);
            accx = fmaf(w3, __int_as_float((int)(b3 << 16)), accx);
            accy = fmaf(w3, __int_as_float((int)(b3 & 0xFFFF0000u)), accy);
        }
        for (; i < rem; ++i) {
            const int   s0 = __shfl(src, i);
            const float w0 = __shfl(wt, i);
            const unsigned b0 = *(const unsigned*)&emb_bf[(size_t)s0 * OUT_DIM + 2 * lane];
            den += w0;
            accx = fmaf(w0, __int_as_float((int)(b0 << 16)), accx);
            accy = fmaf(w0, __int_as_float((int)(b0 & 0xFFFF0000u)), accy);
        }
    }

    const float inv = 1.0f / den;
    float2 o; o.x = accx * inv; o.y = accy * inv;
    *reinterpret_cast<float2*>(&out[(size_t)w * OUT_DIM + 2 * lane]) = o;
}

// ---------------------------------------------------------------------------
extern "C" void kernel_launch(void* const* d_in, const int* in_sizes, int n_in,
                              void* d_out, int out_size, void* d_ws, size_t ws_size,
                              hipStream_t stream)
{
    const float* feats    = (const float*)d_in[0];
    const float* W        = (const float*)d_in[1];
    const float* bias     = (const float*)d_in[2];
    const float* a        = (const float*)d_in[3];
    const int*   edges    = (const int*)d_in[4];
    const int*   node_idx = (const int*)d_in[5];
    float*       out      = (float*)d_out;

    const int n  = in_sizes[0] / IN_DIM;   // 50000
    const int E  = in_sizes[4] / 2;        // 1650000
    const int nb = in_sizes[5];            // 10000

    // Workspace layout (16B-aligned segments):
    char* ws = (char*)d_ws;
    unsigned short* emb_bf = (unsigned short*)ws;
    ws += (size_t)n * OUT_DIM * sizeof(unsigned short);                 // 12.8 MB
    float* s_dst = (float*)ws;  ws += (size_t)(n + 4) * sizeof(float);
    float* s_src = (float*)ws;  ws += (size_t)(n + 4) * sizeof(float);
    int*   needed= (int*)ws;    ws += (size_t)(n + 4) * sizeof(int);
    int*   cur   = (int*)ws;    ws += (size_t)(n + 4) * sizeof(int);
    int2*  ew    = (int2*)ws;   ws += (size_t)n * CAP * sizeof(int2);   // 51.2 MB

    gemm_mfma_kernel<<<(n + 63) / 64, 256, 0, stream>>>(
        feats, W, bias, a, emb_bf, s_dst, s_src, needed, cur, n);
    flag_kernel     <<<(nb + 255) / 256, 256, 0, stream>>>(node_idx, needed, nb);
    scatter_kernel  <<<(E + 255) / 256, 256, 0, stream>>>(edges, needed, cur, s_dst, s_src, ew, E);
    agg_out_kernel  <<<(nb + 3) / 4, 256, 0, stream>>>(node_idx, cur, ew, emb_bf, out, nb);
}

// Round 18
// 63.431 us; speedup vs baseline: 1.2015x; 1.0546x over previous
//
#include <hip/hip_runtime.h>

#define IN_DIM 256
#define OUT_DIM 128
#define SLOPE 0.1f
#define CAP 128   // per-dst bucket capacity; filtered degree ~ Poisson(33), max ~70

typedef short bf16x8 __attribute__((ext_vector_type(8)));
typedef float f32x4  __attribute__((ext_vector_type(4)));

__device__ __forceinline__ unsigned short f2bf(float f) {
    unsigned u = __builtin_bit_cast(unsigned, f);
    return (unsigned short)((u + 0x7FFFu + ((u >> 16) & 1u)) >> 16);   // RNE
}

__device__ __forceinline__ void pack8(const float4& v0, const float4& v1, bf16x8& pk) {
    pk[0]=(short)f2bf(v0.x); pk[1]=(short)f2bf(v0.y);
    pk[2]=(short)f2bf(v0.z); pk[3]=(short)f2bf(v0.w);
    pk[4]=(short)f2bf(v1.x); pk[5]=(short)f2bf(v1.y);
    pk[6]=(short)f2bf(v1.z); pk[7]=(short)f2bf(v1.w);
}

// ---------------------------------------------------------------------------
// Kernel 1: emb = feats @ W^T + b via bf16 MFMA, BM=128, 256 threads.
// R15-proven form (best measured: 63.30us total). Rolling-pipeline staging +
// uniform bounds branch. Fused: s_dst/s_src scores; needed[]/cur[] init.
// ---------------------------------------------------------------------------
__global__ __launch_bounds__(256, 2) void gemm_mfma_kernel(
    const float* __restrict__ feats, const float* __restrict__ W,
    const float* __restrict__ bias, const float* __restrict__ a,
    unsigned short* __restrict__ emb_bf, float* __restrict__ s_dst,
    float* __restrict__ s_src, int* __restrict__ needed,
    int* __restrict__ cur, int n)
{
    __shared__ __align__(16) unsigned short A_s[128 * 128];
    __shared__ __align__(16) unsigned short W_s[128 * 128];
    __shared__ float sd_l[2][128];
    __shared__ float ss_l[2][128];

    const int t    = threadIdx.x;
    const int lane = t & 63;
    const int wid  = t >> 6;
    const int wr   = wid >> 1;
    const int wc   = wid & 1;
    const int row0 = blockIdx.x * 128;

    if (t < 128) {
        const int ci = row0 + t;
        if (ci < n) { needed[ci] = 0; cur[ci] = 0; }
    }

    const int tr = t >> 4;
    const int tc = t & 15;

    const bool full = (row0 + 128 <= n);

    const f32x4 z4 = {0.f, 0.f, 0.f, 0.f};
    f32x4 acc[4][4];
    #pragma unroll
    for (int mi = 0; mi < 4; ++mi)
        #pragma unroll
        for (int ni = 0; ni < 4; ++ni) acc[mi][ni] = z4;

    for (int ph = 0; ph < 2; ++ph) {
        const int k0 = ph * 128;
        if (ph) __syncthreads();

        if (full) {
            {
                const float* pa = &feats[(size_t)(row0 + tr) * IN_DIM + k0 + tc * 8];
                float4 b0[4], b1[4];
                #pragma unroll
                for (int i = 0; i < 4; ++i) {
                    b0[i] = *(const float4*)(pa + (size_t)i * 16 * IN_DIM);
                    b1[i] = *(const float4*)(pa + (size_t)i * 16 * IN_DIM + 4);
                }
                #pragma unroll
                for (int i = 0; i < 8; ++i) {
                    const int r = i * 16 + tr;
                    bf16x8 pk; pack8(b0[i & 3], b1[i & 3], pk);
                    const int off = (r * 128 + tc * 8) ^ ((r & 7) << 3);
                    *(bf16x8*)&A_s[off] = pk;
                    if (i + 4 < 8) {
                        b0[i & 3] = *(const float4*)(pa + (size_t)(i + 4) * 16 * IN_DIM);
                        b1[i & 3] = *(const float4*)(pa + (size_t)(i + 4) * 16 * IN_DIM + 4);
                    }
                }
            }
            {
                const float* pw = &W[(size_t)tr * IN_DIM + k0 + tc * 8];
                float4 b0[4], b1[4];
                #pragma unroll
                for (int i = 0; i < 4; ++i) {
                    b0[i] = *(const float4*)(pw + (size_t)i * 16 * IN_DIM);
                    b1[i] = *(const float4*)(pw + (size_t)i * 16 * IN_DIM + 4);
                }
                #pragma unroll
                for (int i = 0; i < 8; ++i) {
                    const int r = i * 16 + tr;
                    bf16x8 pk; pack8(b0[i & 3], b1[i & 3], pk);
                    const int off = (r * 128 + tc * 8) ^ ((r & 7) << 3);
                    *(bf16x8*)&W_s[off] = pk;
                    if (i + 4 < 8) {
                        b0[i & 3] = *(const float4*)(pw + (size_t)(i + 4) * 16 * IN_DIM);
                        b1[i & 3] = *(const float4*)(pw + (size_t)(i + 4) * 16 * IN_DIM + 4);
                    }
                }
            }
        } else {
            #pragma unroll
            for (int i = 0; i < 8; ++i) {
                const int r = i * 16 + tr;
                const int gr = row0 + r;
                float4 v0 = make_float4(0.f, 0.f, 0.f, 0.f), v1 = v0;
                if (gr < n) {
                    const float* p = &feats[(size_t)gr * IN_DIM + k0 + tc * 8];
                    v0 = *(const float4*)p;
                    v1 = *(const float4*)(p + 4);
                }
                bf16x8 pk; pack8(v0, v1, pk);
                const int off = (r * 128 + tc * 8) ^ ((r & 7) << 3);
                *(bf16x8*)&A_s[off] = pk;
            }
            #pragma unroll
            for (int i = 0; i < 8; ++i) {
                const int r = i * 16 + tr;
                const float* p = &W[(size_t)r * IN_DIM + k0 + tc * 8];
                const float4 v0 = *(const float4*)p;
                const float4 v1 = *(const float4*)(p + 4);
                bf16x8 pk; pack8(v0, v1, pk);
                const int off = (r * 128 + tc * 8) ^ ((r & 7) << 3);
                *(bf16x8*)&W_s[off] = pk;
            }
        }
        __syncthreads();

        #pragma unroll
        for (int ks = 0; ks < 4; ++ks) {
            const int kf = ks * 32 + (lane >> 4) * 8;
            bf16x8 af[4], wf[4];
            #pragma unroll
            for (int mi = 0; mi < 4; ++mi) {
                const int row = wr * 64 + mi * 16 + (lane & 15);
                const int off = (row * 128 + kf) ^ ((row & 7) << 3);
                af[mi] = *(const bf16x8*)&A_s[off];
            }
            #pragma unroll
            for (int ni = 0; ni < 4; ++ni) {
                const int col = wc * 64 + ni * 16 + (lane & 15);
                const int off = (col * 128 + kf) ^ ((col & 7) << 3);
                wf[ni] = *(const bf16x8*)&W_s[off];
            }
            #pragma unroll
            for (int mi = 0; mi < 4; ++mi)
                #pragma unroll
                for (int ni = 0; ni < 4; ++ni)
                    acc[mi][ni] = __builtin_amdgcn_mfma_f32_16x16x32_bf16(
                        af[mi], wf[ni], acc[mi][ni], 0, 0, 0);
        }
    }

    float bcol[4], avd[4], avs[4];
    #pragma unroll
    for (int ni = 0; ni < 4; ++ni) {
        const int col = wc * 64 + ni * 16 + (lane & 15);
        bcol[ni] = bias[col];
        avd[ni]  = a[col];
        avs[ni]  = a[OUT_DIM + col];
    }

    #pragma unroll
    for (int mi = 0; mi < 4; ++mi) {
        #pragma unroll
        for (int j = 0; j < 4; ++j) {
            const int rib = wr * 64 + mi * 16 + (lane >> 4) * 4 + j;
            const int row = row0 + rib;
            float pd = 0.f, ps = 0.f;
            if (row < n) {
                #pragma unroll
                for (int ni = 0; ni < 4; ++ni) {
                    const float v = acc[mi][ni][j] + bcol[ni];
                    emb_bf[(size_t)row * OUT_DIM + wc * 64 + ni * 16 + (lane & 15)] = f2bf(v);
                    pd = fmaf(v, avd[ni], pd);
                    ps = fmaf(v, avs[ni], ps);
                }
            }
            pd += __shfl_xor(pd, 1); ps += __shfl_xor(ps, 1);
            pd += __shfl_xor(pd, 2); ps += __shfl_xor(ps, 2);
            pd += __shfl_xor(pd, 4); ps += __shfl_xor(ps, 4);
            pd += __shfl_xor(pd, 8); ps += __shfl_xor(ps, 8);
            if ((lane & 15) == 0) { sd_l[wc][rib] = pd; ss_l[wc][rib] = ps; }
        }
    }
    __syncthreads();
    if (t < 128) {
        const int row = row0 + t;
        if (row < n) {
            s_dst[row] = sd_l[0][t] + sd_l[1][t];
            s_src[row] = ss_l[0][t] + ss_l[1][t];
        }
    }
}

// ---------------------------------------------------------------------------
// Kernel 2: mark needed destinations (plain store; idempotent)
// ---------------------------------------------------------------------------
__global__ void flag_kernel(const int* __restrict__ node_idx,
                            int* __restrict__ needed, int nb)
{
    const int i = blockIdx.x * blockDim.x + threadIdx.x;
    if (i < nb) needed[node_idx[i]] = 1;
}

// ---------------------------------------------------------------------------
// Kernel 3: needed-filtered scatter into per-dst buckets (R7-proven form).
// ---------------------------------------------------------------------------
__global__ __launch_bounds__(256) void scatter_kernel(
    const int* __restrict__ edges, const int* __restrict__ needed,
    int* __restrict__ cur, const float* __restrict__ s_dst,
    const float* __restrict__ s_src, int2* __restrict__ ew, int E)
{
    const int e = blockIdx.x * blockDim.x + threadIdx.x;
    if (e >= E) return;
    const int2 ed = reinterpret_cast<const int2*>(edges)[e];
    if (needed[ed.x]) {
        const float x = s_dst[ed.x] + s_src[ed.y];
        const float w = __expf(x >= 0.f ? x : SLOPE * x);
        const int p = atomicAdd(&cur[ed.x], 1);
        if (p < CAP)
            ew[(size_t)ed.x * CAP + p] = make_int2(ed.y, __float_as_int(w));
    }
}

// ---------------------------------------------------------------------------
// Kernel 4 (R18): fused aggregate + output, TWO waves per output row.
// Each wave gathers the interleaved half (stride 2) of the bucket — halves
// the dependent-gather chain; partials combined via LDS. Diagnostic: if agg
// is L3-BW-bound this is neutral; if latency-bound, ~-4us.
// ---------------------------------------------------------------------------
__global__ __launch_bounds__(256) void agg_out_kernel(
    const int* __restrict__ node_idx, const int* __restrict__ cur,
    const int2* __restrict__ ew, const unsigned short* __restrict__ emb_bf,
    float* __restrict__ out, int nb)
{
    __shared__ float px[2][64], py[2][64], pdn[2];

    const int t    = threadIdx.x;
    const int lane = t & 63;
    const int lw   = t >> 6;        // local wave 0..3
    const int rs   = lw >> 1;       // row slot 0..1
    const int half = lw & 1;        // bucket half
    const int w    = blockIdx.x * 2 + rs;
    const bool act = (w < nb);

    float accx = 0.f, accy = 0.f, den = 0.f;

    if (act) {
        const int dst = node_idx[w];
        int m = cur[dst];
        if (m > CAP) m = CAP;
        const int2* __restrict__ bucket = ew + (size_t)dst * CAP;

        for (int base = 0; base < m; base += 64) {
            const int rem = min(64, m - base);
            int   src = 0;
            float wt  = 0.f;
            if (lane < rem) {
                const int2 q = bucket[base + lane];
                src = q.x;
                wt  = __int_as_float(q.y);
            }
            int i = half;
            // 4-deep unroll over this wave's stride-2 half
            for (; i + 6 < rem; i += 8) {
                const int   s0 = __shfl(src, i),     s1 = __shfl(src, i + 2);
                const int   s2 = __shfl(src, i + 4), s3 = __shfl(src, i + 6);
                const float w0 = __shfl(wt, i),      w1 = __shfl(wt, i + 2);
                const float w2 = __shfl(wt, i + 4),  w3 = __shfl(wt, i + 6);
                const unsigned b0 = *(const unsigned*)&emb_bf[(size_t)s0 * OUT_DIM + 2 * lane];
                const unsigned b1 = *(const unsigned*)&emb_bf[(size_t)s1 * OUT_DIM + 2 * lane];
                const unsigned b2 = *(const unsigned*)&emb_bf[(size_t)s2 * OUT_DIM + 2 * lane];
                const unsigned b3 = *(const unsigned*)&emb_bf[(size_t)s3 * OUT_DIM + 2 * lane];
                den += (w0 + w1) + (w2 + w3);
                accx = fmaf(w0, __int_as_float((int)(b0 << 16)), accx);
                accy = fmaf(w0, __int_as_float((int)(b0 & 0xFFFF0000u)), accy);
                accx = fmaf(w1, __int_as_float((int)(b1 << 16)), accx);
                accy = fmaf(w1, __int_as_float((int)(b1 & 0xFFFF0000u)), accy);
                accx = fmaf(w2, __int_as_float((int)(b2 << 16)), accx);
                accy = fmaf(w2, __int_as_float((int)(b2 & 0xFFFF0000u)), accy);
                accx = fmaf(w3, __int_as_float((int)(b3 << 16)), accx);
                accy = fmaf(w3, __int_as_float((int)(b3 & 0xFFFF0000u)), accy);
            }
            for (; i < rem; i += 2) {
                const int   s0 = __shfl(src, i);
                const float w0 = __shfl(wt, i);
                const unsigned b0 = *(const unsigned*)&emb_bf[(size_t)s0 * OUT_DIM + 2 * lane];
                den += w0;
                accx = fmaf(w0, __int_as_float((int)(b0 << 16)), accx);
                accy = fmaf(w0, __int_as_float((int)(b0 & 0xFFFF0000u)), accy);
            }
        }
    }

    // combine halves via LDS (barriers unconditional — no divergence)
    if (half) {
        px[rs][lane] = accx;
        py[rs][lane] = accy;
        if (lane == 0) pdn[rs] = den;
    }
    __syncthreads();
    if (!half && act) {
        accx += px[rs][lane];
        accy += py[rs][lane];
        den  += pdn[rs];
        const float inv = 1.0f / den;
        float2 o; o.x = accx * inv; o.y = accy * inv;
        *reinterpret_cast<float2*>(&out[(size_t)w * OUT_DIM + 2 * lane]) = o;
    }
}

// ---------------------------------------------------------------------------
extern "C" void kernel_launch(void* const* d_in, const int* in_sizes, int n_in,
                              void* d_out, int out_size, void* d_ws, size_t ws_size,
                              hipStream_t stream)
{
    const float* feats    = (const float*)d_in[0];
    const float* W        = (const float*)d_in[1];
    const float* bias     = (const float*)d_in[2];
    const float* a        = (const float*)d_in[3];
    const int*   edges    = (const int*)d_in[4];
    const int*   node_idx = (const int*)d_in[5];
    float*       out      = (float*)d_out;

    const int n  = in_sizes[0] / IN_DIM;   // 50000
    const int E  = in_sizes[4] / 2;        // 1650000
    const int nb = in_sizes[5];            // 10000

    // Workspace layout (16B-aligned segments):
    char* ws = (char*)d_ws;
    unsigned short* emb_bf = (unsigned short*)ws;
    ws += (size_t)n * OUT_DIM * sizeof(unsigned short);                 // 12.8 MB
    float* s_dst = (float*)ws;  ws += (size_t)(n + 4) * sizeof(float);
    float* s_src = (float*)ws;  ws += (size_t)(n + 4) * sizeof(float);
    int*   needed= (int*)ws;    ws += (size_t)(n + 4) * sizeof(int);
    int*   cur   = (int*)ws;    ws += (size_t)(n + 4) * sizeof(int);
    int2*  ew    = (int2*)ws;   ws += (size_t)n * CAP * sizeof(int2);   // 51.2 MB

    gemm_mfma_kernel<<<(n + 127) / 128, 256, 0, stream>>>(
        feats, W, bias, a, emb_bf, s_dst, s_src, needed, cur, n);
    flag_kernel     <<<(nb + 255) / 256, 256, 0, stream>>>(node_idx, needed, nb);
    scatter_kernel  <<<(E + 255) / 256, 256, 0, stream>>>(edges, needed, cur, s_dst, s_src, ew, E);
    agg_out_kernel  <<<(nb + 1) / 2, 256, 0, stream>>>(node_idx, cur, ew, emb_bf, out, nb);
}